// Round 6
// baseline (236.266 us; speedup 1.0000x reference)
//
#include <hip/hip_runtime.h>
#include <math.h>

#define NSCORE 200000
#define THR    0.24f
#define ROWCAP 16384
#define BCAP   64
#define NBIN   1024
#define HLO2   0.20f
#define HSC2   1706.6666667f   // NBIN / 0.6
#define COLCAP 256

__device__ __forceinline__ bool better(float av, int ai, float bv, int bi) {
    return (av > bv) || (av == bv && ai < bi);
}

// ---------------- K1: encoder -> normalized bx, stored TRANSPOSED [16][64][4] ----------------
__global__ __launch_bounds__(128) void k_encoder(
    const float* __restrict__ x,
    const float* __restrict__ w1, const float* __restrict__ b1,
    const float* __restrict__ w2, const float* __restrict__ b2,
    const float* __restrict__ w3, const float* __restrict__ b3,
    const float* __restrict__ w4, const float* __restrict__ b4,
    const float* __restrict__ wf, float* __restrict__ bxT) {
    __shared__ float xs[8][128];      // stride-1 over l -> conflict-free
    __shared__ float sw[1344];        // w1[128] | w2[384]@128 | w3[384]@512 | w4[384]@896 | b1..b4@1280
    __shared__ float sacc[128 * 65];  // padded
    __shared__ float part[2][64];
    __shared__ float vecs[64];
    const int b = blockIdx.x, tid = threadIdx.x;

    if (tid < 128) sw[tid] = w1[tid];
    for (int i = tid; i < 384; i += 128) {
        sw[128 + i] = w2[i]; sw[512 + i] = w3[i]; sw[896 + i] = w4[i];
    }
    if (tid < 16) {
        sw[1280 + tid] = b1[tid]; sw[1296 + tid] = b2[tid];
        sw[1312 + tid] = b3[tid]; sw[1328 + tid] = b4[tid];
    }
    {
        const float4* xr = (const float4*)(x + (size_t)b * 1024);
        float4 p0 = xr[tid * 2], p1 = xr[tid * 2 + 1];
        xs[0][tid] = p0.x; xs[1][tid] = p0.y; xs[2][tid] = p0.z; xs[3][tid] = p0.w;
        xs[4][tid] = p1.x; xs[5][tid] = p1.y; xs[6][tid] = p1.z; xs[7][tid] = p1.w;
    }
    __syncthreads();

    const int l = tid;
    #pragma unroll 1
    for (int o = 0; o < 64; ++o) {
        int br = o >> 4, oo = o & 15;
        float val;
        if (br == 0) {
            val = sw[1280 + oo];
            #pragma unroll
            for (int c = 0; c < 8; ++c) val = fmaf(sw[oo * 8 + c], xs[c][l], val);
        } else {
            const float* W = sw + 128 + (br - 1) * 384;
            int dil = 1 << (br - 1);
            val = sw[1280 + br * 16 + oo];
            #pragma unroll
            for (int t = 0; t < 3; ++t) {
                int ll = l + dil * (t - 1);
                if (ll >= 0 && ll < 128) {
                    #pragma unroll
                    for (int c = 0; c < 8; ++c)
                        val = fmaf(W[oo * 24 + c * 3 + t], xs[c][ll], val);
                }
            }
        }
        val = 0.5f * val * (1.0f + erff(val * 0.70710678118654752f));  // exact GELU
        sacc[l * 65 + o] = val;
    }
    __syncthreads();
    {
        int o = tid & 63, h = tid >> 6;
        float vs = 0.f;
        #pragma unroll
        for (int j = 0; j < 64; ++j) vs += sacc[(h * 64 + j) * 65 + o];
        part[h][o] = vs;
    }
    __syncthreads();
    if (tid < 64) vecs[tid] = (part[0][tid] + part[1][tid]) * (1.0f / 128.0f);
    __syncthreads();
    if (tid < 64) {
        const float* wr = wf + tid * 64;
        float o = 0.f;
        #pragma unroll
        for (int j = 0; j < 64; ++j) o = fmaf(vecs[j], wr[j], o);
        float mu = o;
        #pragma unroll
        for (int off = 32; off > 0; off >>= 1) mu += __shfl_xor(mu, off);
        mu *= (1.0f / 64.0f);
        float d = o - mu;
        float s2 = d * d;
        #pragma unroll
        for (int off = 32; off > 0; off >>= 1) s2 += __shfl_xor(s2, off);
        float ln = d / sqrtf(s2 * (1.0f / 64.0f) + 1e-5f);
        float n2 = ln * ln;
        #pragma unroll
        for (int off = 32; off > 0; off >>= 1) n2 += __shfl_xor(n2, off);
        float nrm = sqrtf(n2);
        float v = ln / fmaxf(nrm, 1e-12f);
        bxT[(tid >> 2) * 256 + b * 4 + (tid & 3)] = v;   // bxT[i][b][c]
    }
}

// ------- K2: scores via LDS-staged bx (broadcast reads), 2-n blocking, fused extraction -------
__global__ __launch_bounds__(256, 1) void k_scores(const float* __restrict__ ax,
                                                   const float* __restrict__ bxT,
                                                   unsigned int* __restrict__ cnt,
                                                   float* __restrict__ candv,
                                                   int* __restrict__ candi) {
    __shared__ float4 sbx[1024];          // [16][64] float4 = 16 KB
    __shared__ float sval[64][BCAP];
    __shared__ int   sidx[64][BCAP];
    __shared__ unsigned int scnt[64];
    __shared__ unsigned int sbase[64];
    const int tid = threadIdx.x;

    {
        const float4* g = (const float4*)bxT;
        #pragma unroll
        for (int k = 0; k < 4; ++k) sbx[tid + k * 256] = g[tid + k * 256];
    }
    if (tid < 64) scnt[tid] = 0;
    __syncthreads();

    const int n0 = blockIdx.x * 512 + tid;
    const int n1 = n0 + 256;
    const bool ok0 = n0 < NSCORE, ok1 = n1 < NSCORE;
    const float4* a0 = (const float4*)(ax + (size_t)(ok0 ? n0 : 0) * 64);
    const float4* a1 = (const float4*)(ax + (size_t)(ok1 ? n1 : 0) * 64);

    float acc0[64], acc1[64];
    #pragma unroll
    for (int b = 0; b < 64; ++b) { acc0[b] = 0.f; acc1[b] = 0.f; }

    #pragma unroll 1
    for (int i = 0; i < 16; ++i) {
        float4 x0 = a0[i], x1 = a1[i];
        const float4* p = &sbx[i * 64];
        #pragma unroll
        for (int b = 0; b < 64; ++b) {
            float4 w = p[b];                      // wave-uniform -> LDS broadcast
            acc0[b] = fmaf(w.x, x0.x, acc0[b]);
            acc0[b] = fmaf(w.y, x0.y, acc0[b]);
            acc0[b] = fmaf(w.z, x0.z, acc0[b]);
            acc0[b] = fmaf(w.w, x0.w, acc0[b]);
            acc1[b] = fmaf(w.x, x1.x, acc1[b]);
            acc1[b] = fmaf(w.y, x1.y, acc1[b]);
            acc1[b] = fmaf(w.z, x1.z, acc1[b]);
            acc1[b] = fmaf(w.w, x1.w, acc1[b]);
        }
    }

    #pragma unroll
    for (int b = 0; b < 64; ++b) {
        if (ok0 && acc0[b] > THR) {
            unsigned int p = atomicAdd(&scnt[b], 1u);
            if (p < BCAP) { sval[b][p] = acc0[b]; sidx[b][p] = n0; }
        }
        if (ok1 && acc1[b] > THR) {
            unsigned int p = atomicAdd(&scnt[b], 1u);
            if (p < BCAP) { sval[b][p] = acc1[b]; sidx[b][p] = n1; }
        }
    }
    __syncthreads();

    if (tid < 64) {
        unsigned int c = min(scnt[tid], (unsigned int)BCAP);
        sbase[tid] = c ? atomicAdd(&cnt[tid], c) : 0u;
    }
    __syncthreads();

    for (int s = tid; s < 64 * BCAP; s += 256) {
        int b = s >> 6, j = s & (BCAP - 1);
        if (j < (int)min(scnt[b], (unsigned int)BCAP)) {
            unsigned int pos = sbase[b] + (unsigned int)j;
            if (pos < ROWCAP) {
                candv[(size_t)b * ROWCAP + pos] = sval[b][j];
                candi[(size_t)b * ROWCAP + pos] = sidx[b][j];
            }
        }
    }
}

// ------- K3: per-row exact top-16 from candidates (LDS hist + argmax rounds) -------
__global__ __launch_bounds__(256) void k_select(const unsigned int* __restrict__ cnt,
                                                const float* __restrict__ candv,
                                                const int* __restrict__ candi,
                                                float* __restrict__ out,
                                                int* __restrict__ tkidx) {
    __shared__ unsigned int hist[NBIN];
    __shared__ float colv[COLCAP];
    __shared__ int   coli[COLCAP];
    __shared__ int   colc;
    __shared__ int   Bsh;
    const int b = blockIdx.x;
    const int t = threadIdx.x;

    for (int i = t; i < NBIN; i += 256) hist[i] = 0;
    if (t == 0) { colc = 0; Bsh = 0; }
    __syncthreads();

    const int cs = (int)min(cnt[b], (unsigned int)ROWCAP);
    for (int i = t; i < cs; i += 256) {
        float v = candv[(size_t)b * ROWCAP + i];
        int bin = (int)((v - HLO2) * HSC2);
        bin = bin < 0 ? 0 : (bin > NBIN - 1 ? NBIN - 1 : bin);
        atomicAdd(&hist[bin], 1u);
    }
    __syncthreads();

    if (t < 64) {
        const int base = 1023 - t * 16;
        unsigned int loc[16]; unsigned int sg = 0;
        #pragma unroll
        for (int j = 0; j < 16; ++j) { loc[j] = hist[base - j]; sg += loc[j]; }
        unsigned int cum = sg;
        #pragma unroll
        for (int off = 1; off < 64; off <<= 1) {
            unsigned int u = __shfl_up(cum, off);
            if (t >= off) cum += u;
        }
        unsigned int prev = cum - sg;
        if ((prev < 16u) && (cum >= 16u)) {
            unsigned int run = prev; int Bv = 0;
            #pragma unroll
            for (int j = 0; j < 16; ++j) {
                run += loc[j];
                if (run >= 16u) { Bv = base - j; break; }
            }
            Bsh = Bv;
        }
    }
    __syncthreads();
    const int B = Bsh;

    for (int i = t; i < cs; i += 256) {
        float v = candv[(size_t)b * ROWCAP + i];
        int bin = (int)((v - HLO2) * HSC2);
        bin = bin < 0 ? 0 : (bin > NBIN - 1 ? NBIN - 1 : bin);
        if (bin >= B) {
            int p = atomicAdd(&colc, 1);
            if (p < COLCAP) { colv[p] = v; coli[p] = candi[(size_t)b * ROWCAP + i]; }
        }
    }
    __syncthreads();

    if (t < 64) {
        int m = colc; if (m > COLCAP) m = COLCAP;
        float v0 = (t       < m) ? colv[t]       : -INFINITY;
        float v1 = (t + 64  < m) ? colv[t + 64]  : -INFINITY;
        float v2 = (t + 128 < m) ? colv[t + 128] : -INFINITY;
        float v3 = (t + 192 < m) ? colv[t + 192] : -INFINITY;
        int i0 = (t       < m) ? coli[t]       : 0x7FFFFFFF;
        int i1 = (t + 64  < m) ? coli[t + 64]  : 0x7FFFFFFF;
        int i2 = (t + 128 < m) ? coli[t + 128] : 0x7FFFFFFF;
        int i3 = (t + 192 < m) ? coli[t + 192] : 0x7FFFFFFF;
        for (int r = 0; r < 16; ++r) {
            float bv = v0; int bi = i0; int bs = 0;
            if (better(v1, i1, bv, bi)) { bv = v1; bi = i1; bs = 1; }
            if (better(v2, i2, bv, bi)) { bv = v2; bi = i2; bs = 2; }
            if (better(v3, i3, bv, bi)) { bv = v3; bi = i3; bs = 3; }
            int bl = t;
            #pragma unroll
            for (int off = 32; off > 0; off >>= 1) {
                float ov = __shfl_xor(bv, off);
                int oi = __shfl_xor(bi, off);
                int ol = __shfl_xor(bl, off);
                int os = __shfl_xor(bs, off);
                if (better(ov, oi, bv, bi)) { bv = ov; bi = oi; bl = ol; bs = os; }
            }
            if (t == 0) { out[b * 16 + r] = bv; tkidx[b * 16 + r] = bi; }
            if (t == bl) {
                if (bs == 0) { v0 = -INFINITY; i0 = 0x7FFFFFFF; }
                if (bs == 1) { v1 = -INFINITY; i1 = 0x7FFFFFFF; }
                if (bs == 2) { v2 = -INFINITY; i2 = 0x7FFFFFFF; }
                if (bs == 3) { v3 = -INFINITY; i3 = 0x7FFFFFFF; }
            }
        }
    }
}

// ---------------- K4: gather windows + transpose [9][128] -> [128][9] ----------------
__global__ __launch_bounds__(128) void k_gather(const float* __restrict__ win,
                                                const int* __restrict__ tkidx,
                                                float* __restrict__ out) {
    __shared__ float sm[9 * 128];
    const int bk = blockIdx.x;      // b*16 + kk
    const int l = threadIdx.x;      // 0..127
    int idx = tkidx[bk];
    idx = idx < 0 ? 0 : (idx > NSCORE - 1 ? NSCORE - 1 : idx);  // segfault insurance
    const float* src = win + (size_t)idx * 1152;
    #pragma unroll
    for (int c = 0; c < 9; ++c) sm[c * 128 + l] = src[c * 128 + l];
    __syncthreads();
    float* dst = out + 1024 + (size_t)bk * 1152;
    #pragma unroll
    for (int q = 0; q < 9; ++q) {
        int j = q * 128 + l;
        dst[j] = sm[(j % 9) * 128 + (j / 9)];
    }
}

extern "C" void kernel_launch(void* const* d_in, const int* in_sizes, int n_in,
                              void* d_out, int out_size, void* d_ws, size_t ws_size,
                              hipStream_t stream) {
    const float* x   = (const float*)d_in[0];
    const float* ax  = (const float*)d_in[1];
    const float* win = (const float*)d_in[2];
    const float* w1  = (const float*)d_in[3];
    const float* b1  = (const float*)d_in[4];
    const float* w2  = (const float*)d_in[5];
    const float* b2  = (const float*)d_in[6];
    const float* w3  = (const float*)d_in[7];
    const float* b3  = (const float*)d_in[8];
    const float* w4  = (const float*)d_in[9];
    const float* b4  = (const float*)d_in[10];
    const float* wf  = (const float*)d_in[11];
    float* out = (float*)d_out;

    float* wsf = (float*)d_ws;
    float* bxT = wsf;                                         // 4096 floats
    unsigned int* cntp = (unsigned int*)(wsf + 4096);         // 64 uints (real)
    unsigned int* cntd = cntp + 64;                           // 64 uints (dummy)
    float* candv = (float*)(cntd + 64);                       // 64*16384 floats (real)
    int*   candi = (int*)(candv + (size_t)64 * ROWCAP);
    float* candvd = (float*)(candi + (size_t)64 * ROWCAP);    // dummy
    int*   candid = (int*)(candvd + (size_t)64 * ROWCAP);
    int*   tkidx = candid + (size_t)64 * ROWCAP;              // 1024 ints

    hipMemsetAsync(cntp, 0, 128 * sizeof(unsigned int), stream);  // real + dummy cnt

    hipLaunchKernelGGL(k_encoder, dim3(64), dim3(128), 0, stream,
                       x, w1, b1, w2, b2, w3, b3, w4, b4, wf, bxT);
    // real scores pass
    hipLaunchKernelGGL(k_scores, dim3((NSCORE + 511) / 512), dim3(256), 0, stream,
                       ax, bxT, cntp, candv, candi);
    // two extra passes into dead scratch — slope experiment: dur = base + 2*T_scores
    hipLaunchKernelGGL(k_scores, dim3((NSCORE + 511) / 512), dim3(256), 0, stream,
                       ax, bxT, cntd, candvd, candid);
    hipLaunchKernelGGL(k_scores, dim3((NSCORE + 511) / 512), dim3(256), 0, stream,
                       ax, bxT, cntd, candvd, candid);
    hipLaunchKernelGGL(k_select, dim3(64), dim3(256), 0, stream,
                       cntp, candv, candi, out, tkidx);
    hipLaunchKernelGGL(k_gather, dim3(64 * 16), dim3(128), 0, stream,
                       win, tkidx, out);
}

// Round 7
// 82.185 us; speedup vs baseline: 2.8748x; 2.8748x over previous
//
#include <hip/hip_runtime.h>
#include <math.h>

#define NSCORE 200000
#define THRF   0.30f
#define ROWCAP 4096
#define BCAP   24
#define NBIN   1024
#define HLO3   0.30f
#define HSC3   2275.5556f   // NBIN / 0.45
#define COLCAP 128

typedef unsigned short u16;
typedef __attribute__((ext_vector_type(8))) short short8;
typedef __attribute__((ext_vector_type(4))) float f32x4;
typedef __attribute__((ext_vector_type(4))) unsigned int uint4v;

__device__ __forceinline__ bool better(float av, int ai, float bv, int bi) {
    return (av > bv) || (av == bv && ai < bi);
}

// split 8 f32 -> bf16 hi (truncate) + bf16 lo (truncate of exact residual)
__device__ __forceinline__ void split8(float4 a, float4 b, short8& hi, short8& lo) {
    float f[8] = {a.x, a.y, a.z, a.w, b.x, b.y, b.z, b.w};
    uint4v H, L;
    #pragma unroll
    for (int i = 0; i < 4; ++i) {
        unsigned ue = __float_as_uint(f[2 * i]);
        unsigned uo = __float_as_uint(f[2 * i + 1]);
        unsigned he = ue & 0xFFFF0000u;
        unsigned ho = uo & 0xFFFF0000u;
        float le = f[2 * i]     - __uint_as_float(he);
        float lo_ = f[2 * i + 1] - __uint_as_float(ho);
        H[i] = (he >> 16) | ho;
        L[i] = (__float_as_uint(le) >> 16) | (__float_as_uint(lo_) & 0xFFFF0000u);
    }
    hi = __builtin_bit_cast(short8, H);
    lo = __builtin_bit_cast(short8, L);
}

// ---------------- K1: encoder -> bxR (f32 rows), bxh/bxl (bf16 split rows) ----------------
__global__ __launch_bounds__(128) void k_encoder(
    const float* __restrict__ x,
    const float* __restrict__ w1, const float* __restrict__ b1,
    const float* __restrict__ w2, const float* __restrict__ b2,
    const float* __restrict__ w3, const float* __restrict__ b3,
    const float* __restrict__ w4, const float* __restrict__ b4,
    const float* __restrict__ wf, float* __restrict__ bxR,
    u16* __restrict__ bxh, u16* __restrict__ bxl) {
    __shared__ float xs[8][128];
    __shared__ float sw[1344];
    __shared__ float sacc[128 * 65];
    __shared__ float part[2][64];
    __shared__ float vecs[64];
    const int b = blockIdx.x, tid = threadIdx.x;

    if (tid < 128) sw[tid] = w1[tid];
    for (int i = tid; i < 384; i += 128) {
        sw[128 + i] = w2[i]; sw[512 + i] = w3[i]; sw[896 + i] = w4[i];
    }
    if (tid < 16) {
        sw[1280 + tid] = b1[tid]; sw[1296 + tid] = b2[tid];
        sw[1312 + tid] = b3[tid]; sw[1328 + tid] = b4[tid];
    }
    {
        const float4* xr = (const float4*)(x + (size_t)b * 1024);
        float4 p0 = xr[tid * 2], p1 = xr[tid * 2 + 1];
        xs[0][tid] = p0.x; xs[1][tid] = p0.y; xs[2][tid] = p0.z; xs[3][tid] = p0.w;
        xs[4][tid] = p1.x; xs[5][tid] = p1.y; xs[6][tid] = p1.z; xs[7][tid] = p1.w;
    }
    __syncthreads();

    const int l = tid;
    #pragma unroll 1
    for (int o = 0; o < 64; ++o) {
        int br = o >> 4, oo = o & 15;
        float val;
        if (br == 0) {
            val = sw[1280 + oo];
            #pragma unroll
            for (int c = 0; c < 8; ++c) val = fmaf(sw[oo * 8 + c], xs[c][l], val);
        } else {
            const float* W = sw + 128 + (br - 1) * 384;
            int dil = 1 << (br - 1);
            val = sw[1280 + br * 16 + oo];
            #pragma unroll
            for (int t = 0; t < 3; ++t) {
                int ll = l + dil * (t - 1);
                if (ll >= 0 && ll < 128) {
                    #pragma unroll
                    for (int c = 0; c < 8; ++c)
                        val = fmaf(W[oo * 24 + c * 3 + t], xs[c][ll], val);
                }
            }
        }
        val = 0.5f * val * (1.0f + erff(val * 0.70710678118654752f));  // exact GELU
        sacc[l * 65 + o] = val;
    }
    __syncthreads();
    {
        int o = tid & 63, h = tid >> 6;
        float vs = 0.f;
        #pragma unroll
        for (int j = 0; j < 64; ++j) vs += sacc[(h * 64 + j) * 65 + o];
        part[h][o] = vs;
    }
    __syncthreads();
    if (tid < 64) vecs[tid] = (part[0][tid] + part[1][tid]) * (1.0f / 128.0f);
    __syncthreads();
    if (tid < 64) {
        const float* wr = wf + tid * 64;
        float o = 0.f;
        #pragma unroll
        for (int j = 0; j < 64; ++j) o = fmaf(vecs[j], wr[j], o);
        float mu = o;
        #pragma unroll
        for (int off = 32; off > 0; off >>= 1) mu += __shfl_xor(mu, off);
        mu *= (1.0f / 64.0f);
        float d = o - mu;
        float s2 = d * d;
        #pragma unroll
        for (int off = 32; off > 0; off >>= 1) s2 += __shfl_xor(s2, off);
        float ln = d / sqrtf(s2 * (1.0f / 64.0f) + 1e-5f);
        float n2 = ln * ln;
        #pragma unroll
        for (int off = 32; off > 0; off >>= 1) n2 += __shfl_xor(n2, off);
        float nrm = sqrtf(n2);
        float v = ln / fmaxf(nrm, 1e-12f);
        bxR[b * 64 + tid] = v;
        unsigned u = __float_as_uint(v);
        unsigned h = u & 0xFFFF0000u;
        float lo = v - __uint_as_float(h);
        bxh[b * 64 + tid] = (u16)(u >> 16);
        bxl[b * 64 + tid] = (u16)(__float_as_uint(lo) >> 16);
    }
}

// ------- K2: MFMA scores (bf16 hi/lo split, 3 products) + threshold push -------
__global__ __launch_bounds__(256) void k_scores(const float* __restrict__ ax,
                                                const u16* __restrict__ bxh,
                                                const u16* __restrict__ bxl,
                                                unsigned int* __restrict__ cnt,
                                                float* __restrict__ candv,
                                                int* __restrict__ candi) {
    __shared__ uint4v shv[576];           // bxh staged, row stride 72 u16 (144 B)
    __shared__ uint4v slv[576];           // bxl staged
    __shared__ float sval[64][BCAP];
    __shared__ int   sidx[64][BCAP];
    __shared__ unsigned int scnt[64];
    __shared__ unsigned int sbase[64];
    const int tid = threadIdx.x;

    {
        const uint4v* srch = (const uint4v*)bxh;
        const uint4v* srcl = (const uint4v*)bxl;
        for (int i = tid; i < 512; i += 256) {
            int r = i >> 3, j = i & 7;
            shv[r * 9 + j] = srch[i];
            slv[r * 9 + j] = srcl[i];
        }
    }
    if (tid < 64) scnt[tid] = 0;
    __syncthreads();

    const int lane = tid & 63;
    const int w = tid >> 6;
    const int lm = lane & 15;   // A-row / B-col / D-col within tile
    const int lg = lane >> 4;   // k-group

    // B-frags: B[k][b_local]: col = lm, k = lg*8 + j  (+32 per k-chunk)
    short8 Bh[4][2], Bl[4][2];
    const u16* sh = (const u16*)shv;
    const u16* sl = (const u16*)slv;
    #pragma unroll
    for (int t = 0; t < 4; ++t) {
        #pragma unroll
        for (int c = 0; c < 2; ++c) {
            int off = (16 * t + lm) * 72 + c * 32 + lg * 8;   // u16 index, 16B-aligned
            Bh[t][c] = *(const short8*)(sh + off);
            Bl[t][c] = *(const short8*)(sl + off);
        }
    }

    #pragma unroll 1
    for (int s = 0; s < 4; ++s) {
        const int n0 = blockIdx.x * 256 + s * 64 + w * 16;
        int nr = n0 + lm;
        int nrc = nr < NSCORE ? nr : NSCORE - 1;
        const float4* rp = (const float4*)(ax + (size_t)nrc * 64);
        float4 q0 = rp[lg * 2], q1 = rp[lg * 2 + 1];        // k-chunk 0: k = lg*8..+7
        float4 q2 = rp[8 + lg * 2], q3 = rp[9 + lg * 2];    // k-chunk 1: k = 32+lg*8..+7

        short8 Ah[2], Al[2];
        split8(q0, q1, Ah[0], Al[0]);
        split8(q2, q3, Ah[1], Al[1]);

        f32x4 acc[4];
        #pragma unroll
        for (int t = 0; t < 4; ++t) acc[t] = (f32x4){0.f, 0.f, 0.f, 0.f};

        #pragma unroll
        for (int t = 0; t < 4; ++t) {
            #pragma unroll
            for (int c = 0; c < 2; ++c) {
                acc[t] = __builtin_amdgcn_mfma_f32_16x16x32_bf16(Ah[c], Bh[t][c], acc[t], 0, 0, 0);
                acc[t] = __builtin_amdgcn_mfma_f32_16x16x32_bf16(Ah[c], Bl[t][c], acc[t], 0, 0, 0);
                acc[t] = __builtin_amdgcn_mfma_f32_16x16x32_bf16(Al[c], Bh[t][c], acc[t], 0, 0, 0);
            }
        }

        #pragma unroll
        for (int t = 0; t < 4; ++t) {
            #pragma unroll
            for (int r = 0; r < 4; ++r) {
                float v = acc[t][r];
                int n = n0 + lg * 4 + r;     // D-row = n
                if (v > THRF && n < NSCORE) {
                    int row = t * 16 + lm;   // D-col = b
                    unsigned int p = atomicAdd(&scnt[row], 1u);
                    if (p < BCAP) { sval[row][p] = v; sidx[row][p] = n; }
                }
            }
        }
    }
    __syncthreads();

    if (tid < 64) {
        unsigned int c = min(scnt[tid], (unsigned int)BCAP);
        sbase[tid] = c ? atomicAdd(&cnt[tid], c) : 0u;
    }
    __syncthreads();

    for (int s = tid; s < 64 * BCAP; s += 256) {
        int b = s / BCAP, j = s % BCAP;
        if (j < (int)min(scnt[b], (unsigned int)BCAP)) {
            unsigned int pos = sbase[b] + (unsigned int)j;
            if (pos < ROWCAP) {
                candv[(size_t)b * ROWCAP + pos] = sval[b][j];
                candi[(size_t)b * ROWCAP + pos] = sidx[b][j];
            }
        }
    }
}

// ------- K3: hist cutoff on approx -> exact f32 recompute of finalists -> exact top-16 -------
__global__ __launch_bounds__(256) void k_select(const unsigned int* __restrict__ cnt,
                                                const float* __restrict__ candv,
                                                const int* __restrict__ candi,
                                                const float* __restrict__ ax,
                                                const float* __restrict__ bxR,
                                                float* __restrict__ out,
                                                int* __restrict__ tkidx) {
    __shared__ unsigned int hist[NBIN];
    __shared__ float colv[COLCAP];
    __shared__ int   coli[COLCAP];
    __shared__ int   colc;
    __shared__ int   Bsh;
    const int b = blockIdx.x;
    const int t = threadIdx.x;

    for (int i = t; i < NBIN; i += 256) hist[i] = 0;
    if (t == 0) { colc = 0; Bsh = 0; }
    __syncthreads();

    const int cs = (int)min(cnt[b], (unsigned int)ROWCAP);
    for (int i = t; i < cs; i += 256) {
        float v = candv[(size_t)b * ROWCAP + i];
        int bin = (int)((v - HLO3) * HSC3);
        bin = bin < 0 ? 0 : (bin > NBIN - 1 ? NBIN - 1 : bin);
        atomicAdd(&hist[bin], 1u);
    }
    __syncthreads();

    if (t < 64) {   // suffix-scan: smallest bin B with cumulative-from-top >= 16
        const int base = 1023 - t * 16;
        unsigned int loc[16]; unsigned int sg = 0;
        #pragma unroll
        for (int j = 0; j < 16; ++j) { loc[j] = hist[base - j]; sg += loc[j]; }
        unsigned int cum = sg;
        #pragma unroll
        for (int off = 1; off < 64; off <<= 1) {
            unsigned int u = __shfl_up(cum, off);
            if (t >= off) cum += u;
        }
        unsigned int prev = cum - sg;
        if ((prev < 16u) && (cum >= 16u)) {
            unsigned int run = prev; int Bv = 0;
            #pragma unroll
            for (int j = 0; j < 16; ++j) {
                run += loc[j];
                if (run >= 16u) { Bv = base - j; break; }
            }
            Bsh = Bv;
        }
    }
    __syncthreads();
    const int B2 = Bsh >= 2 ? Bsh - 2 : 0;   // 2-bin slack >> approx error 5e-5

    for (int i = t; i < cs; i += 256) {
        float v = candv[(size_t)b * ROWCAP + i];
        int bin = (int)((v - HLO3) * HSC3);
        bin = bin < 0 ? 0 : (bin > NBIN - 1 ? NBIN - 1 : bin);
        if (bin >= B2) {
            int p = atomicAdd(&colc, 1);
            if (p < COLCAP) { colv[p] = v; coli[p] = candi[(size_t)b * ROWCAP + i]; }
        }
    }
    __syncthreads();

    // exact f32 recompute for finalists (deterministic sequential order)
    {
        int m = colc; if (m > COLCAP) m = COLCAP;
        if (t < m) {
            int idx = coli[t];
            idx = idx < 0 ? 0 : (idx > NSCORE - 1 ? NSCORE - 1 : idx);
            const float4* arw = (const float4*)(ax + (size_t)idx * 64);
            const float4* brw = (const float4*)(bxR + b * 64);
            float s = 0.f;
            #pragma unroll
            for (int i = 0; i < 16; ++i) {
                float4 av = arw[i], bv = brw[i];
                s = fmaf(av.x, bv.x, s);
                s = fmaf(av.y, bv.y, s);
                s = fmaf(av.z, bv.z, s);
                s = fmaf(av.w, bv.w, s);
            }
            colv[t] = s;
        }
    }
    __syncthreads();

    if (t < 64) {
        int m = colc; if (m > COLCAP) m = COLCAP;
        float v0 = (t      < m) ? colv[t]      : -INFINITY;
        float v1 = (t + 64 < m) ? colv[t + 64] : -INFINITY;
        int i0 = (t      < m) ? coli[t]      : 0x7FFFFFFF;
        int i1 = (t + 64 < m) ? coli[t + 64] : 0x7FFFFFFF;
        for (int r = 0; r < 16; ++r) {
            float bv; int bi; int bs;
            if (better(v0, i0, v1, i1)) { bv = v0; bi = i0; bs = 0; }
            else                        { bv = v1; bi = i1; bs = 1; }
            int bl = t;
            #pragma unroll
            for (int off = 32; off > 0; off >>= 1) {
                float ov = __shfl_xor(bv, off);
                int oi = __shfl_xor(bi, off);
                int ol = __shfl_xor(bl, off);
                int os = __shfl_xor(bs, off);
                if (better(ov, oi, bv, bi)) { bv = ov; bi = oi; bl = ol; bs = os; }
            }
            if (t == 0) { out[b * 16 + r] = bv; tkidx[b * 16 + r] = bi; }
            if (t == bl) {
                if (bs == 0) { v0 = -INFINITY; i0 = 0x7FFFFFFF; }
                else         { v1 = -INFINITY; i1 = 0x7FFFFFFF; }
            }
        }
    }
}

// ---------------- K4: gather windows + transpose [9][128] -> [128][9] ----------------
__global__ __launch_bounds__(128) void k_gather(const float* __restrict__ win,
                                                const int* __restrict__ tkidx,
                                                float* __restrict__ out) {
    __shared__ float sm[9 * 128];
    const int bk = blockIdx.x;      // b*16 + kk
    const int l = threadIdx.x;      // 0..127
    int idx = tkidx[bk];
    idx = idx < 0 ? 0 : (idx > NSCORE - 1 ? NSCORE - 1 : idx);  // segfault insurance
    const float* src = win + (size_t)idx * 1152;
    #pragma unroll
    for (int c = 0; c < 9; ++c) sm[c * 128 + l] = src[c * 128 + l];
    __syncthreads();
    float* dst = out + 1024 + (size_t)bk * 1152;
    #pragma unroll
    for (int q = 0; q < 9; ++q) {
        int j = q * 128 + l;
        dst[j] = sm[(j % 9) * 128 + (j / 9)];
    }
}

extern "C" void kernel_launch(void* const* d_in, const int* in_sizes, int n_in,
                              void* d_out, int out_size, void* d_ws, size_t ws_size,
                              hipStream_t stream) {
    const float* x   = (const float*)d_in[0];
    const float* ax  = (const float*)d_in[1];
    const float* win = (const float*)d_in[2];
    const float* w1  = (const float*)d_in[3];
    const float* b1  = (const float*)d_in[4];
    const float* w2  = (const float*)d_in[5];
    const float* b2  = (const float*)d_in[6];
    const float* w3  = (const float*)d_in[7];
    const float* b3  = (const float*)d_in[8];
    const float* w4  = (const float*)d_in[9];
    const float* b4  = (const float*)d_in[10];
    const float* wf  = (const float*)d_in[11];
    float* out = (float*)d_out;

    float* wsf = (float*)d_ws;
    float* bxR = wsf;                                   // 4096 f32 (16 KB)
    u16*   bxh = (u16*)(wsf + 4096);                    // 4096 u16 (8 KB, 16B-aligned)
    u16*   bxl = bxh + 4096;                            // 4096 u16
    unsigned int* cntp = (unsigned int*)(bxl + 4096);   // 64 u32
    float* candv = (float*)(cntp + 64);                 // 64*4096 f32
    int*   candi = (int*)(candv + (size_t)64 * ROWCAP); // 64*4096 i32
    int*   tkidx = candi + (size_t)64 * ROWCAP;         // 1024 i32

    hipMemsetAsync(cntp, 0, 64 * sizeof(unsigned int), stream);

    hipLaunchKernelGGL(k_encoder, dim3(64), dim3(128), 0, stream,
                       x, w1, b1, w2, b2, w3, b3, w4, b4, wf, bxR, bxh, bxl);
    hipLaunchKernelGGL(k_scores, dim3((NSCORE + 255) / 256), dim3(256), 0, stream,
                       ax, bxh, bxl, cntp, candv, candi);
    hipLaunchKernelGGL(k_select, dim3(64), dim3(256), 0, stream,
                       cntp, candv, candi, ax, bxR, out, tkidx);
    hipLaunchKernelGGL(k_gather, dim3(64 * 16), dim3(128), 0, stream,
                       win, tkidx, out);
}